// Round 7
// baseline (260.684 us; speedup 1.0000x reference)
//
#include <hip/hip_runtime.h>

#define DD 256        // D
#define SS 256        // S
#define BB 64         // B
#define NEDGE 500000  // E
#define MM 2048       // M
#define NEG_INF -10000000000.0f
#define ROWF4 512     // float4 stride between consecutive (b,s) type rows in token_reprs
#define NROWS (BB * SS)  // 16384

#define EBLK ((NEDGE + 255) / 256)   // 1954 edge blocks
#define LMBLK (BB * 4 * 8)           // 2048 lm blocks
#define FUSE_GRID 4096               // even ids -> edge, odd ids -> lm

// workspace byte offsets (ws is 512 MB per harness poison fills)
#define OFF_VC     0
#define OFF_MSORT  4096
#define OFF_BSTART (4096 + MM * 4)
#define OFF_FSLAB  (1 << 16)                  // fp8 table, 16384 x 256 B = 4 MB
#define OFF_P2     ((1 << 16) + (4 << 20))    // bf16 row-major, 8 MB
#define OFF_MROWS  ((1 << 16) + (12 << 20))   // bf16 mask rows, 512 KB

typedef float vf4 __attribute__((ext_vector_type(4)));
typedef float f32x2 __attribute__((ext_vector_type(2)));
typedef float f32x4 __attribute__((ext_vector_type(4)));
typedef short bf16x8 __attribute__((ext_vector_type(8)));

__device__ __forceinline__ float bflo(unsigned u) { return __uint_as_float(u << 16); }
__device__ __forceinline__ float bfhi(unsigned u) { return __uint_as_float(u & 0xFFFF0000u); }
__device__ __forceinline__ unsigned short bf_rne(float f) {
    unsigned u = __float_as_uint(f);
    return (unsigned short)((u + 0x7FFFu + ((u >> 16) & 1u)) >> 16);
}
__device__ __forceinline__ unsigned pack2_rne(float a, float b) {
    return (unsigned)bf_rne(a) | ((unsigned)bf_rne(b) << 16);
}

// ---- fp8 e4m3 helpers: prefer HW cvt (OCP on gfx950); SW fallback kept
// format-consistent (encode+decode pair used together only).
#if __has_builtin(__builtin_amdgcn_cvt_pk_fp8_f32) && __has_builtin(__builtin_amdgcn_cvt_pk_f32_fp8)
#define FP8_HW 1
#else
#define FP8_HW 0
#endif

__device__ __forceinline__ unsigned char sw_f32_to_e4m3(float f) {
    unsigned u = __float_as_uint(f);
    unsigned s = (u >> 24) & 0x80u;
    float af = fabsf(f);
    if (af >= 448.f) return (unsigned char)(s | 0x7E);
    if (af < 0.015625f) {
        int q = (int)(af * 512.f + 0.5f);
        return (unsigned char)(s | (unsigned)q);
    }
    unsigned lsb = (u >> 20) & 1u;
    u += 0x7FFFFu + lsb;
    int e = (int)(u >> 23) - 120;
    unsigned m = (u >> 20) & 7u;
    if (e >= 16) return (unsigned char)(s | 0x7E);
    return (unsigned char)(s | ((unsigned)e << 3) | m);
}
__device__ __forceinline__ float sw_e4m3_to_f32(unsigned b) {
    unsigned s = (b & 0x80u) << 24;
    unsigned e = (b >> 3) & 0xFu, m = b & 7u;
    if (e == 0) {
        float v = (float)m * 0.001953125f;
        return (b & 0x80u) ? -v : v;
    }
    return __uint_as_float(s | ((e + 120u) << 23) | (m << 20));
}

__device__ __forceinline__ unsigned enc_fp8x4(float x, float y, float z, float w) {
#if FP8_HW
    int r = 0;
    r = __builtin_amdgcn_cvt_pk_fp8_f32(x, y, r, false);
    r = __builtin_amdgcn_cvt_pk_fp8_f32(z, w, r, true);
    return (unsigned)r;
#else
    return (unsigned)sw_f32_to_e4m3(x) | ((unsigned)sw_f32_to_e4m3(y) << 8)
         | ((unsigned)sw_f32_to_e4m3(z) << 16) | ((unsigned)sw_f32_to_e4m3(w) << 24);
#endif
}

__device__ __forceinline__ float dot4_fp8(unsigned aw, unsigned bw, const float4 v) {
#if FP8_HW
    f32x2 al = __builtin_amdgcn_cvt_pk_f32_fp8((int)aw, false);
    f32x2 ah = __builtin_amdgcn_cvt_pk_f32_fp8((int)aw, true);
    f32x2 bl = __builtin_amdgcn_cvt_pk_f32_fp8((int)bw, false);
    f32x2 bh = __builtin_amdgcn_cvt_pk_f32_fp8((int)bw, true);
    return (al.x * bl.x) * v.x + (al.y * bl.y) * v.y
         + (ah.x * bh.x) * v.z + (ah.y * bh.y) * v.w;
#else
    return sw_e4m3_to_f32(aw & 255u) * sw_e4m3_to_f32(bw & 255u) * v.x
         + sw_e4m3_to_f32((aw >> 8) & 255u) * sw_e4m3_to_f32((bw >> 8) & 255u) * v.y
         + sw_e4m3_to_f32((aw >> 16) & 255u) * sw_e4m3_to_f32((bw >> 16) & 255u) * v.z
         + sw_e4m3_to_f32(aw >> 24) * sw_e4m3_to_f32(bw >> 24) * v.w;
#endif
}

// Fused prep kernel (unchanged from round 6):
//  blocks [0, NROWS/4): type rows -> fslab (fp8 row-major) + p2 (bf16 row-major)
//  blocks [NROWS/4, +MM/4): mask rows via lm_indices -> mrows (bf16 row-major)
//  block NROWS/4+MM/4:   vc[d] = sum_j w1[d,j]*w2[j], vc[256] = b1.w2+b2
//  block NROWS/4+MM/4+1: counting-sort m by batch pointer
__global__ __launch_bounds__(256) void prep(
        const float* __restrict__ tok, const int* __restrict__ lmi,
        const float* __restrict__ w1, const float* __restrict__ b1,
        const float* __restrict__ w2, const float* __restrict__ b2,
        const int* __restrict__ bp,
        unsigned* __restrict__ fslab,
        unsigned* __restrict__ p2, unsigned* __restrict__ mrows,
        float* __restrict__ vc, int* __restrict__ msorted,
        int* __restrict__ bstart) {
    const int t = threadIdx.x;
    const int lane = t & 63;
    const int w    = t >> 6;
    if (blockIdx.x < NROWS / 4) {
        const int row = blockIdx.x * 4 + w;
        const float4 a = ((const float4*)tok)[(size_t)row * ROWF4 + lane];
        fslab[(size_t)row * 64 + lane] = enc_fp8x4(a.x, a.y, a.z, a.w);
        const size_t pi = (size_t)row * 128 + lane * 2;
        p2[pi]     = pack2_rne(a.x, a.y);
        p2[pi + 1] = pack2_rne(a.z, a.w);
    } else if (blockIdx.x < NROWS / 4 + MM / 4) {
        const int m = (blockIdx.x - NROWS / 4) * 4 + w;
        const float4 a = ((const float4*)(tok + (size_t)lmi[m] * DD))[lane];
        mrows[(size_t)m * 128 + lane * 2]     = pack2_rne(a.x, a.y);
        mrows[(size_t)m * 128 + lane * 2 + 1] = pack2_rne(a.z, a.w);
    } else if (blockIdx.x == NROWS / 4 + MM / 4) {
        __shared__ float sw2[DD / 2];
        if (t < DD / 2) sw2[t] = w2[t];
        __syncthreads();
        for (int r = w; r < DD; r += 4) {
            float x = w1[r * (DD / 2) + lane] * sw2[lane]
                    + w1[r * (DD / 2) + 64 + lane] * sw2[64 + lane];
            x += __shfl_down(x, 32);
            x += __shfl_down(x, 16);
            x += __shfl_down(x, 8);
            x += __shfl_down(x, 4);
            x += __shfl_down(x, 2);
            x += __shfl_down(x, 1);
            if (lane == 0) vc[r] = x;
        }
        if (w == 0) {
            float x = b1[lane] * sw2[lane] + b1[64 + lane] * sw2[64 + lane];
            x += __shfl_down(x, 32);
            x += __shfl_down(x, 16);
            x += __shfl_down(x, 8);
            x += __shfl_down(x, 4);
            x += __shfl_down(x, 2);
            x += __shfl_down(x, 1);
            if (lane == 0) vc[DD] = x + b2[0];
        }
    } else {
        __shared__ int hist[BB];
        __shared__ int offs[BB + 1];
        if (t < BB) hist[t] = 0;
        __syncthreads();
        for (int m = t; m < MM; m += 256) atomicAdd(&hist[bp[m]], 1);
        __syncthreads();
        if (t == 0) {
            int acc = 0;
            for (int i = 0; i < BB; ++i) { offs[i] = acc; acc += hist[i]; }
            offs[BB] = acc;
        }
        __syncthreads();
        if (t < BB + 1) bstart[t] = offs[t];
        __syncthreads();
        for (int m = t; m < MM; m += 256) {
            int pos = atomicAdd(&offs[bp[m]], 1);
            msorted[pos] = m;
        }
    }
}

// FUSED edge + lm kernel. Even blockIdx -> edge (proven fp8 gather path,
// memory-latency-bound); odd blockIdx -> lm MFMA (compute-bound). Interleaved
// IDs co-schedule both on each CU so lm's MFMA work runs in the shadow of
// edge's gather stalls. lm path reads MFMA fragments DIRECTLY from global
// (no big LDS tiles) so the fused kernel keeps ~3.4KB LDS and edge occupancy
// is unchanged; __launch_bounds__(256,8) pins VGPR<=64 for 8 waves/SIMD.
__global__ __launch_bounds__(256, 8) void edge_lm(
        const unsigned* __restrict__ fslab,
        const int* __restrict__ edges, const float* __restrict__ vc,
        float* __restrict__ out_lemmas,
        const unsigned* __restrict__ p2,
        const unsigned* __restrict__ mrows,
        const int* __restrict__ msorted,
        const int* __restrict__ bstart,
        const int* __restrict__ tpm,
        float* __restrict__ out_lm) {
    const int t = threadIdx.x;
    const int lane = t & 63;

    __shared__ int sIdx[2][256];
    __shared__ float accs[256];
    __shared__ int mids[32];
    __shared__ int sact[64];
    __shared__ int snact;

    if ((blockIdx.x & 1) == 0) {
        // ---------------- edge path (unchanged structure) ----------------
        const int eb = blockIdx.x >> 1;
        if (eb >= EBLK) return;
        const int w = t >> 6;
        const int l16 = lane & 15;
        const int g = lane >> 4;
        const int e0 = eb * 256;

        const int e = e0 + t;
        const bool val = e < NEDGE;
        sIdx[0][t] = val ? __builtin_nontemporal_load(edges + e) : 0;
        sIdx[1][t] = val ? __builtin_nontemporal_load(edges + NEDGE + e) : 0;

        const float4 v0 = ((const float4*)vc)[l16 * 4 + 0];
        const float4 v1 = ((const float4*)vc)[l16 * 4 + 1];
        const float4 v2 = ((const float4*)vc)[l16 * 4 + 2];
        const float4 v3 = ((const float4*)vc)[l16 * 4 + 3];
        __syncthreads();

        #pragma unroll 4
        for (int it = 0; it < 16; ++it) {
            const int slot = w * 64 + it * 4 + g;
            const int sc = sIdx[0][slot];
            const int gl = sIdx[1][slot];
            const uint4 A = *(const uint4*)(fslab + (size_t)sc * 64 + l16 * 4);
            const uint4 B = *(const uint4*)(fslab + (size_t)gl * 64 + l16 * 4);
            float s = dot4_fp8(A.x, B.x, v0) + dot4_fp8(A.y, B.y, v1)
                    + dot4_fp8(A.z, B.z, v2) + dot4_fp8(A.w, B.w, v3);
            s += __shfl_down(s, 8, 16);
            s += __shfl_down(s, 4, 16);
            s += __shfl_down(s, 2, 16);
            s += __shfl_down(s, 1, 16);
            if (l16 == 0) accs[slot] = s;
        }
        __syncthreads();
        const float c = vc[DD];
        if (val) __builtin_nontemporal_store(accs[t] + c, out_lemmas + e);
    } else {
        // ---------------- lm path: MFMA with direct-global fragments ------
        const int li = blockIdx.x >> 1;   // 0..2047
        const int ch = li & 7;
        const int st = (li >> 3) & 3;
        const int b  = li >> 5;
        const int s0 = bstart[b], s1 = bstart[b + 1];
        const int base = s0 + ch * 32;
        if (base >= s1) return;
        const int nm = min(32, s1 - base);

        if (t < 32) mids[t] = msorted[base + min(t, nm - 1)];
        if (t >= 64 && t < 128) {  // wave 1: ballot-compact active columns
            int lt = t - 64;
            bool act = tpm[b * SS + st * 64 + lt] != 0;
            unsigned long long mk = __ballot(act);
            if (act) sact[__popcll(mk & ((1ull << lt) - 1))] = lt;
            if (lt == 0) snact = (int)__popcll(mk);
        }
        __syncthreads();

        for (int f = t; f < nm * 64; f += 256) {
            int i = f >> 6, c = f & 63;
            if (!tpm[b * SS + st * 64 + c])
                out_lm[(size_t)mids[i] * SS + st * 64 + c] = NEG_INF;
        }

        const int nact = snact;
        const int wv = t >> 6;        // 4 waves
        const int rt = wv >> 1;       // mask half 0..1
        const int ct = wv & 1;        // col-tile within g 0..1
        const int fr = lane & 15;
        const int fq = lane >> 4;

        const size_t arow = (size_t)mids[rt * 16 + fr] * 128;   // mrows row base (uints)

        for (int g = 0; g * 32 < nact; ++g) {
            const int jg = g * 32 + ct * 16 + fr;
            const int sj = sact[min(jg, nact - 1)];             // clamp: guarded at write
            const size_t brow = ((size_t)b * SS + st * 64 + sj) * 128;

            f32x4 acc = {0.f, 0.f, 0.f, 0.f};
            #pragma unroll
            for (int stp = 0; stp < 8; ++stp) {
                bf16x8 a  = *(const bf16x8*)&mrows[arow + stp * 16 + fq * 4];
                bf16x8 bf = *(const bf16x8*)&p2[brow + stp * 16 + fq * 4];
                acc = __builtin_amdgcn_mfma_f32_16x16x32_bf16(a, bf, acc, 0, 0, 0);
            }

            // D: col = lane&15 (s within tile), row = (lane>>4)*4 + r (mask)
            if (jg < nact) {
                #pragma unroll
                for (int r = 0; r < 4; ++r) {
                    const int mi = rt * 16 + fq * 4 + r;
                    if (mi < nm) out_lm[(size_t)mids[mi] * SS + st * 64 + sj] = acc[r];
                }
            }
        }
    }
}

extern "C" void kernel_launch(void* const* d_in, const int* in_sizes, int n_in,
                              void* d_out, int out_size, void* d_ws, size_t ws_size,
                              hipStream_t stream) {
    const float* tok = (const float*)d_in[0];
    const float* w1  = (const float*)d_in[1];
    const float* b1  = (const float*)d_in[2];
    const float* w2  = (const float*)d_in[3];
    const float* b2  = (const float*)d_in[4];
    const int* edges = (const int*)d_in[5];
    const int* lmi   = (const int*)d_in[6];
    const int* bp    = (const int*)d_in[7];
    const int* tpm   = (const int*)d_in[8];

    float* out_lemmas = (float*)d_out;
    float* out_lm     = (float*)d_out + NEDGE;

    char* ws = (char*)d_ws;
    float* vc        = (float*)(ws + OFF_VC);
    int* msorted     = (int*)(ws + OFF_MSORT);
    int* bstart      = (int*)(ws + OFF_BSTART);
    unsigned* fslab  = (unsigned*)(ws + OFF_FSLAB);
    unsigned* p2     = (unsigned*)(ws + OFF_P2);
    unsigned* mrows  = (unsigned*)(ws + OFF_MROWS);

    prep<<<NROWS / 4 + MM / 4 + 2, 256, 0, stream>>>(
        tok, lmi, w1, b1, w2, b2, bp, fslab, p2, mrows, vc, msorted, bstart);
    edge_lm<<<FUSE_GRID, 256, 0, stream>>>(
        fslab, edges, vc, out_lemmas, p2, mrows, msorted, bstart, tpm, out_lm);
}